// Round 6
// baseline (135.137 us; speedup 1.0000x reference)
//
#include <hip/hip_runtime.h>
#include <math.h>

#define T 20
#define MAXA 9408
#define APB 12348            // anchors per image (9408+2352+588)
#define LOSS_OFF 16          // float index into ws: 192*3 loss triples
#define KEY_OFF  2048        // u32 index into ws: 64*APB keys
#define MF_BYTE_OFF (4 * (KEY_OFF + 64 * APB))

static __device__ __forceinline__ unsigned mapf(float x) {
    unsigned u = __float_as_uint(x);
    return (u & 0x80000000u) ? ~u : (u | 0x80000000u);
}
static __device__ __forceinline__ float unmapf(unsigned m) {
    return __uint_as_float((m & 0x80000000u) ? (m ^ 0x80000000u) : ~m);
}
static __device__ __forceinline__ float bce_pos(float x) {
    return fmaxf(x, 0.f) - x + log1pf(expf(-fabsf(x)));
}
static __device__ __forceinline__ float bce_neg(float x) {
    return fmaxf(x, 0.f) + log1pf(expf(-fabsf(x)));
}

// ---------------------------------------------------------------------------
// K1: per-anchor matching. 704 blocks x 256. 5 contiguous anchors/thread,
// per-box band-skip test. Writes keys (u32) + flags (u16) to ws.
// ---------------------------------------------------------------------------
__global__ __launch_bounds__(256) void match_kernel(
    const float* __restrict__ pred1, const float* __restrict__ pred2,
    const float* __restrict__ pred3, const float* __restrict__ tboxes,
    unsigned* __restrict__ wsu, unsigned short* __restrict__ mf)
{
#pragma clang fp contract(off)
    const int blk = blockIdx.x;
    const int b = blk / 11, c = blk - 11 * b;
    int s, j0;
    if (c < 8)       { s = 0; j0 = c * 1176; }
    else if (c < 10) { s = 1; j0 = (c - 8) * 1176; }
    else             { s = 2; j0 = 0; }
    const float* __restrict__ pred = (s == 0) ? pred1 : (s == 1) ? pred2 : pred3;
    const int W = 56 >> s, HW = W * W, A = 3 * HW;
    const float stf = (float)(8 << s);
    const int sh = 3 - s;
    const int lim = min(1176, A - j0);

    __shared__ float4 s_box[T];
    __shared__ float  s_ab[T];
    const int tid = threadIdx.x;

    if (tid < T) {
        float4 g = ((const float4*)tboxes)[b * T + tid];
        s_box[tid] = g;
        s_ab[tid]  = (g.z - g.x) * (g.w - g.y);
    }
    __syncthreads();

    float ax[5], ay[5], az[5], aw[5], ar[5], bn[5], bu[5];
    int at_[5], kk[5], pp[5];
    bool vv[5];
    float xlo = 1e30f, xhi = -1e30f, ylo = 1e30f, yhi = -1e30f;
    const int obase = 5 * tid;
#pragma unroll
    for (int r = 0; r < 5; r++) {
        int o = obase + r;
        vv[r] = (o < lim);
        int j = j0 + (vv[r] ? o : 0);
        int k   = (j >= HW) + (j >= 2 * HW);
        int pix = j - k * HW;
        int qq  = pix >> sh;
        int py  = (qq * 9363) >> 16;   // exact /7 for qq<=448
        int px  = pix - py * W;
        float w  = (2.0f + 0.5f * (float)k) * stf;   // exact f32
        float cx = ((float)px + 0.5f) * stf;
        float cy = ((float)py + 0.5f) * stf;
        ax[r] = cx - 0.5f * w; ay[r] = cy - 0.5f * w;
        az[r] = cx + 0.5f * w; aw[r] = cy + 0.5f * w;
        ar[r] = w * w;
        bn[r] = 0.f; bu[r] = 1.f; at_[r] = 0;   // iou==0 -> argmax t=0
        kk[r] = k; pp[r] = pix;
        xlo = fminf(xlo, ax[r]); xhi = fmaxf(xhi, az[r]);
        ylo = fminf(ylo, ay[r]); yhi = fmaxf(yhi, aw[r]);
    }

    for (int t = 0; t < T; t++) {
        float4 g = s_box[t];
        // disjoint-from-band => IoU exactly 0 for all 5 anchors => skip
        if (g.x < xhi && g.z > xlo && g.y < yhi && g.w > ylo) {
            float ab = s_ab[t];
#pragma unroll
            for (int r = 0; r < 5; r++) {
                float lx = fmaxf(ax[r], g.x), ly = fmaxf(ay[r], g.y);
                float rx = fminf(az[r], g.z), ry = fminf(aw[r], g.w);
                float ww = fmaxf(rx - lx, 0.f), hh = fmaxf(ry - ly, 0.f);
                float inter = ww * hh;
                float u = ((ar[r] + ab) - inter) + 1e-9f;
                if (inter * bu[r] > bn[r] * u) { bn[r] = inter; bu[r] = u; at_[r] = t; }
            }
        }
    }

    const float* objbase = pred + (size_t)(b * 24 + 4) * HW;
    const unsigned base = (unsigned)(b * APB + ((s == 0) ? 0 : (s == 1) ? 9408 : 11760));
#pragma unroll
    for (int r = 0; r < 5; r++) {
        if (vv[r]) {
            int j = j0 + obase + r;
            bool pos = (bn[r] + bn[r] >= bu[r]);   // max_iou >= 0.5
            bool neg = (bn[r] < 0.3f * bu[r]);     // max_iou <  0.3
            unsigned key = 0u;
            if (neg) key = mapf(objbase[(size_t)kk[r] * 8 * HW + pp[r]]);
            wsu[KEY_OFF + base + j] = key;
            mf[base + j] = (unsigned short)(at_[r] | (pos ? 0x100 : 0) | (neg ? 0x200 : 0));
        }
    }
}

// ---------------------------------------------------------------------------
// K2: per-(b,s). Keys/flags in LDS; no per-thread arrays (no scratch).
// Forced positives + 4x8-bit radix select (wave-pair-private hists) + losses.
// 192 blocks x 512.
// ---------------------------------------------------------------------------
__global__ __launch_bounds__(512) void select_loss_kernel(
    const float* __restrict__ pred1, const float* __restrict__ pred2,
    const float* __restrict__ pred3, const float* __restrict__ tboxes,
    const int* __restrict__ tlabels,
    const unsigned* __restrict__ wsu, const unsigned short* __restrict__ mf,
    float* __restrict__ wsf)
{
#pragma clang fp contract(off)
    const int bid = blockIdx.x;
    const int b = bid / 3, s = bid - 3 * b;
    const float* __restrict__ pred = (s == 0) ? pred1 : (s == 1) ? pred2 : pred3;
    const int W = 56 >> s, HW = W * W, A = 3 * HW;
    const float stf = (float)(8 << s);
    const int sh = 3 - s;
    const unsigned base = (unsigned)(b * APB + ((s == 0) ? 0 : (s == 1) ? 9408 : 11760));

    __shared__ unsigned       s_key[MAXA];
    __shared__ unsigned short s_mf[MAXA];
    __shared__ float4   s_box[T];
    __shared__ float    s_ab[T];
    __shared__ int      s_lab[T];
    __shared__ int      s_besta[T];
    __shared__ unsigned whist[4][256];
    __shared__ unsigned s_npnn;
    __shared__ unsigned s_bc[2];
    __shared__ float    s_redf[8 * 4];

    const int tid = threadIdx.x, lane = tid & 63, wid = tid >> 6;

    if (tid < T) {
        float4 g = ((const float4*)tboxes)[b * T + tid];
        s_box[tid] = g;
        s_ab[tid]  = (g.z - g.x) * (g.w - g.y);
        s_lab[tid] = tlabels[b * T + tid];
    }
    if (tid == 0) s_npnn = 0u;
    __syncthreads();

    // ---- A: keys + flags global -> LDS (coalesced) -------------------------
    for (int j = tid; j < A; j += 512) {
        s_key[j] = wsu[KEY_OFF + base + j];
        s_mf[j]  = mf[base + j];
    }

    // ---- B: windowed per-box best anchor (one wave per box) ----------------
    for (int t = wid; t < T; t += 8) {
        float4 g = s_box[t];
        float  ab = s_ab[t];
        int px0 = max(0, (int)floorf(g.x / stf) - 2);
        int px1 = min(W - 1, (int)floorf(g.z / stf) + 2);
        int py0 = max(0, (int)floorf(g.y / stf) - 2);
        int py1 = min(W - 1, (int)floorf(g.w / stf) + 2);
        int rowlen = (px1 - px0 + 1) * 3;
        float bi = -1.f, bu2 = 1.f;
        int ba = 0;
        for (int py = py0; py <= py1; py++) {
            float cy = ((float)py + 0.5f) * stf;
            for (int cc = lane; cc < rowlen; cc += 64) {
                int ix = (cc * 21846) >> 16;   // /3
                int k  = cc - 3 * ix;
                int px = px0 + ix;
                float w  = (2.0f + 0.5f * (float)k) * stf;
                float cx = ((float)px + 0.5f) * stf;
                float lx = fmaxf(cx - 0.5f * w, g.x), ly = fmaxf(cy - 0.5f * w, g.y);
                float rx = fminf(cx + 0.5f * w, g.z), ry = fminf(cy + 0.5f * w, g.w);
                float ww = fmaxf(rx - lx, 0.f), hh = fmaxf(ry - ly, 0.f);
                float inter = ww * hh;
                float u = ((w * w + ab) - inter) + 1e-9f;
                if (inter * bu2 > bi * u) {
                    bi = inter; bu2 = u; ba = (py * W + px) * 3 + k;
                }
            }
        }
        for (int off = 32; off; off >>= 1) {
            float oi = __shfl_down(bi, off, 64);
            float ou = __shfl_down(bu2, off, 64);
            int   oa = __shfl_down(ba, off, 64);
            float l = oi * bu2, r = bi * ou;
            if (l > r || (l == r && oa < ba)) { bi = oi; bu2 = ou; ba = oa; }
        }
        if (lane == 0) {
            int pix = (ba * 21846) >> 16;   // /3
            int k = ba - 3 * pix;
            s_besta[t] = k * HW + pix;      // flattened j
        }
    }
    __syncthreads();   // A writes + s_besta complete

    // ---- forced-positive overrides (last t wins; distinct anchors -> no race)
    if (tid < T) {
        int j20 = s_besta[tid];
        bool winner = true;
        for (int t2 = tid + 1; t2 < T; t2++) if (s_besta[t2] == j20) winner = false;
        if (winner) {
            s_mf[j20]  = (unsigned short)(tid | 0x100);
            s_key[j20] = 0u;
        }
    }
    __syncthreads();

    // ---- np/nn counted post-override ---------------------------------------
    unsigned npnn = 0;
    for (int j = tid; j < A; j += 512) {
        unsigned m = s_mf[j];
        npnn += ((m >> 8) & 1u) + (((m >> 9) & 1u) << 16);
    }
    for (int off = 32; off; off >>= 1) npnn += (unsigned)__shfl_down((int)npnn, off, 64);
    if (lane == 0) atomicAdd(&s_npnn, npnn);
    __syncthreads();
    unsigned np = s_npnn & 0xFFFFu, nn = s_npnn >> 16;
    unsigned need = min(3u * np, nn);

    // ---- exact k-th largest neg key: 4x8-bit radix, wave-pair-private hists
    unsigned kth = 0xFFFFFFFFu;
    if (need > 0) {
        unsigned prefix = 0, remaining = need;
        for (int p = 0; p < 4; p++) {
            const int sh_ = 24 - 8 * p;
            if (tid < 256) {
                whist[0][tid] = 0; whist[1][tid] = 0;
                whist[2][tid] = 0; whist[3][tid] = 0;
            }
            __syncthreads();
            for (int j = tid; j < A; j += 512) {
                unsigned k = s_key[j];
                bool ok = (p == 0) || ((k >> (sh_ + 8)) == prefix);
                if (ok) atomicAdd(&whist[wid >> 1][(k >> sh_) & 255u], 1u);
            }
            __syncthreads();
            if (tid < 256) {
                whist[0][tid] = whist[0][tid] + whist[1][tid]
                              + whist[2][tid] + whist[3][tid];
            }
            __syncthreads();
            if (wid == 0) {
                int b0 = lane * 4;
                unsigned csum = whist[0][b0] + whist[0][b0 + 1]
                              + whist[0][b0 + 2] + whist[0][b0 + 3];
                unsigned Tv = csum;
                for (int off = 1; off < 64; off <<= 1) {
                    unsigned o = __shfl_down(Tv, off, 64);
                    if (lane + off < 64) Tv += o;
                }
                // Tv = suffix sum over bins >= b0 (non-increasing in lane)
                unsigned long long ball = __ballot(Tv >= remaining);
                int L = 63 - __clzll(ball);
                if (lane == L) {
                    unsigned sv = Tv - csum;   // count strictly above chunk
                    int bb = b0 + 3;
                    while (true) { sv += whist[0][bb]; if (sv >= remaining) break; bb--; }
                    s_bc[0] = (unsigned)bb;
                    s_bc[1] = sv - whist[0][bb];  // count strictly above bin bb
                }
            }
            __syncthreads();
            remaining -= s_bc[1];
            prefix = (prefix << 8) | s_bc[0];
        }
        kth = prefix;
    }

    // ---- losses ------------------------------------------------------------
    float obj_s = 0.f, cls_s = 0.f, loc_s = 0.f;
    unsigned cgt = 0;
    for (int j = tid; j < A; j += 512) {
        unsigned mfv = s_mf[j];
        if (mfv & 0x100u) {
            int k   = (j >= HW) + (j >= 2 * HW);
            int pix = j - k * HW;
            const float* bp = pred + (size_t)(b * 24 + k * 8) * HW + pix;
            float x = bp[(size_t)4 * HW];
            obj_s += bce_pos(x);
            int t = mfv & 0xFFu;
            float4 g = s_box[t];
            int tgt = s_lab[t] - 1;
            float c0 = bp[(size_t)5 * HW], c1 = bp[(size_t)6 * HW], c2 = bp[(size_t)7 * HW];
            float mm  = fmaxf(c0, fmaxf(c1, c2));
            float lse = logf(expf(c0 - mm) + expf(c1 - mm) + expf(c2 - mm));
            float ct = (tgt == 0) ? c0 : (tgt == 1) ? c1 : c2;
            cls_s += (mm + lse) - ct;
            int qq = pix >> sh;
            int py = (qq * 9363) >> 16;
            int px = pix - py * W;
            float w  = (2.0f + 0.5f * (float)k) * stf;
            float cx = ((float)px + 0.5f) * stf;
            float cy = ((float)py + 0.5f) * stf;
            float gcx = (g.x + g.z) * 0.5f, gcy = (g.y + g.w) * 0.5f;
            float gw = g.z - g.x, gh = g.w - g.y;
            float t0 = (gcx - cx) / w, t1 = (gcy - cy) / w;
            float t2 = logf(gw / w),   t3 = logf(gh / w);
            float d0 = bp[0], d1 = bp[(size_t)HW], d2 = bp[(size_t)2 * HW], d3 = bp[(size_t)3 * HW];
            float dd;
            dd = fabsf(d0 - t0); loc_s += (dd < 1.f) ? 0.5f * dd * dd : dd - 0.5f;
            dd = fabsf(d1 - t1); loc_s += (dd < 1.f) ? 0.5f * dd * dd : dd - 0.5f;
            dd = fabsf(d2 - t2); loc_s += (dd < 1.f) ? 0.5f * dd * dd : dd - 0.5f;
            dd = fabsf(d3 - t3); loc_s += (dd < 1.f) ? 0.5f * dd * dd : dd - 0.5f;
        } else {
            unsigned key = s_key[j];
            if (key > kth) { obj_s += bce_neg(unmapf(key)); cgt++; }
        }
    }
    for (int off = 32; off; off >>= 1) {
        obj_s += __shfl_down(obj_s, off, 64);
        cls_s += __shfl_down(cls_s, off, 64);
        loc_s += __shfl_down(loc_s, off, 64);
        cgt   += (unsigned)__shfl_down((int)cgt, off, 64);
    }
    if (lane == 0) {
        s_redf[wid * 4 + 0] = obj_s;
        s_redf[wid * 4 + 1] = cls_s;
        s_redf[wid * 4 + 2] = loc_s;
        s_redf[wid * 4 + 3] = __uint_as_float(cgt);
    }
    __syncthreads();
    if (tid == 0) {
        float ob = 0.f, cl = 0.f, lc = 0.f;
        unsigned cg = 0;
        for (int w2 = 0; w2 < 8; w2++) {
            ob += s_redf[w2 * 4 + 0];
            cl += s_redf[w2 * 4 + 1];
            lc += s_redf[w2 * 4 + 2];
            cg += __float_as_uint(s_redf[w2 * 4 + 3]);
        }
        if (need > 0) ob += (float)(need - cg) * bce_neg(unmapf(kth));
        wsf[LOSS_OFF + bid * 3 + 0] = ob / (float)max(np + need, 1u);
        wsf[LOSS_OFF + bid * 3 + 1] = cl / (float)max(np, 1u);
        wsf[LOSS_OFF + bid * 3 + 2] = lc / (float)max(4u * np, 1u);
    }
}

__global__ void finalize_kernel(const float* __restrict__ wsf,
                                float* __restrict__ out) {
    const int t = threadIdx.x, lane = t & 63, wid = t >> 6;
    __shared__ float red[12];
    float v0 = 0.f, v1 = 0.f, v2 = 0.f;
    if (t < 192) {
        v0 = wsf[LOSS_OFF + 3 * t];
        v1 = wsf[LOSS_OFF + 3 * t + 1];
        v2 = wsf[LOSS_OFF + 3 * t + 2];
    }
    for (int off = 32; off; off >>= 1) {
        v0 += __shfl_down(v0, off, 64);
        v1 += __shfl_down(v1, off, 64);
        v2 += __shfl_down(v2, off, 64);
    }
    if (lane == 0) { red[wid * 3] = v0; red[wid * 3 + 1] = v1; red[wid * 3 + 2] = v2; }
    __syncthreads();
    if (t == 0) {
        float obj = 0.f, cls = 0.f, loc = 0.f;
        for (int w2 = 0; w2 < 4; w2++) {
            obj += red[w2 * 3]; cls += red[w2 * 3 + 1]; loc += red[w2 * 3 + 2];
        }
        obj /= 64.f; cls /= 64.f; loc /= 64.f;
        out[0] = obj; out[1] = cls; out[2] = loc;
        out[3] = obj + cls + 2.f * loc;
    }
}

extern "C" void kernel_launch(void* const* d_in, const int* in_sizes, int n_in,
                              void* d_out, int out_size, void* d_ws, size_t ws_size,
                              hipStream_t stream) {
    const float* pred1   = (const float*)d_in[0];
    const float* pred2   = (const float*)d_in[1];
    const float* pred3   = (const float*)d_in[2];
    const float* tboxes  = (const float*)d_in[6];
    const int*   tlabels = (const int*)d_in[7];
    unsigned* wsu = (unsigned*)d_ws;
    unsigned short* mf = (unsigned short*)((char*)d_ws + MF_BYTE_OFF);
    float* wsf = (float*)d_ws;
    float* out = (float*)d_out;

    match_kernel<<<64 * 11, 256, 0, stream>>>(pred1, pred2, pred3, tboxes, wsu, mf);
    select_loss_kernel<<<64 * 3, 512, 0, stream>>>(
        pred1, pred2, pred3, tboxes, tlabels, wsu, mf, wsf);
    finalize_kernel<<<1, 256, 0, stream>>>(wsf, out);
}

// Round 7
// 116.862 us; speedup vs baseline: 1.1564x; 1.1564x over previous
//
#include <hip/hip_runtime.h>
#include <math.h>

#define T 20
#define MAXA 9408
#define LOSS_OFF 16          // float index into ws: 192*3 loss triples

static __device__ __forceinline__ unsigned mapf(float x) {
    unsigned u = __float_as_uint(x);
    return (u & 0x80000000u) ? ~u : (u | 0x80000000u);
}
static __device__ __forceinline__ float unmapf(unsigned m) {
    return __uint_as_float((m & 0x80000000u) ? (m ^ 0x80000000u) : ~m);
}
static __device__ __forceinline__ float bce_pos(float x) {
    return fmaxf(x, 0.f) - x + log1pf(expf(-fabsf(x)));
}
static __device__ __forceinline__ float bce_neg(float x) {
    return fmaxf(x, 0.f) + log1pf(expf(-fabsf(x)));
}

// ---------------------------------------------------------------------------
// Fused per-(b,s) kernel, 192 blocks x 1024. All per-anchor state in LDS
// (no cross-phase register arrays -> no scratch). Match writes keys/flags
// straight to LDS; radix select with wave-quad-private histograms.
// ---------------------------------------------------------------------------
__global__ __launch_bounds__(1024, 1) void fused_kernel(
    const float* __restrict__ pred1, const float* __restrict__ pred2,
    const float* __restrict__ pred3, const float* __restrict__ tboxes,
    const int* __restrict__ tlabels, float* __restrict__ wsf)
{
#pragma clang fp contract(off)
    const int bid = blockIdx.x;
    const int b = bid / 3, s = bid - 3 * b;
    const float* __restrict__ pred = (s == 0) ? pred1 : (s == 1) ? pred2 : pred3;
    const int W = 56 >> s, HW = W * W, A = 3 * HW;
    const float stf = (float)(8 << s);
    const int sh = 3 - s;

    __shared__ unsigned       s_key[MAXA];   // 37632 B
    __shared__ unsigned short s_mf[MAXA];    // 18816 B
    __shared__ float4   s_box[T];
    __shared__ float    s_ab[T];
    __shared__ int      s_lab[T];
    __shared__ int      s_besta[T];
    __shared__ unsigned whist[4][256];       // 4096 B
    __shared__ unsigned s_npnn;
    __shared__ unsigned s_bc[2];
    __shared__ float    s_redf[16 * 4];

    const int tid = threadIdx.x, lane = tid & 63, wid = tid >> 6;

    if (tid < T) {
        float4 g = ((const float4*)tboxes)[b * T + tid];
        s_box[tid] = g;
        s_ab[tid]  = (g.z - g.x) * (g.w - g.y);
        s_lab[tid] = tlabels[b * T + tid];
    }
    if (tid == 0) s_npnn = 0u;
    __syncthreads();

    const float* objbase = pred + (size_t)(b * 24 + 4) * HW;

    // ---- match: groups of 4 contiguous anchors, band-skip, results -> LDS --
    for (int j0 = 4 * tid; j0 < A; j0 += 4096) {
        float ax[4], ay[4], az[4], aw[4], ar[4], bn[4], bu[4];
        int at_[4];
        float xlo = 1e30f, xhi = -1e30f, ylo = 1e30f, yhi = -1e30f;
#pragma unroll
        for (int r = 0; r < 4; r++) {
            int j = j0 + r;                   // A % 4 == 0 -> all 4 valid
            int k   = (j >= HW) + (j >= 2 * HW);
            int pix = j - k * HW;
            int qq  = pix >> sh;
            int py  = (qq * 9363) >> 16;      // exact /7 for qq<=448
            int px  = pix - py * W;
            float w  = (2.0f + 0.5f * (float)k) * stf;   // exact f32
            float cx = ((float)px + 0.5f) * stf;
            float cy = ((float)py + 0.5f) * stf;
            ax[r] = cx - 0.5f * w; ay[r] = cy - 0.5f * w;
            az[r] = cx + 0.5f * w; aw[r] = cy + 0.5f * w;
            ar[r] = w * w;
            bn[r] = 0.f; bu[r] = 1.f; at_[r] = 0;   // iou==0 -> argmax t=0
            xlo = fminf(xlo, ax[r]); xhi = fmaxf(xhi, az[r]);
            ylo = fminf(ylo, ay[r]); yhi = fmaxf(yhi, aw[r]);
        }
        for (int t = 0; t < T; t++) {
            float4 g = s_box[t];
            // disjoint from the 4-anchor band => IoU exactly 0 => skip
            if (g.x < xhi && g.z > xlo && g.y < yhi && g.w > ylo) {
                float ab = s_ab[t];
#pragma unroll
                for (int r = 0; r < 4; r++) {
                    float lx = fmaxf(ax[r], g.x), ly = fmaxf(ay[r], g.y);
                    float rx = fminf(az[r], g.z), ry = fminf(aw[r], g.w);
                    float ww = fmaxf(rx - lx, 0.f), hh = fmaxf(ry - ly, 0.f);
                    float inter = ww * hh;
                    float u = ((ar[r] + ab) - inter) + 1e-9f;
                    if (inter * bu[r] > bn[r] * u) {
                        bn[r] = inter; bu[r] = u; at_[r] = t;
                    }
                }
            }
        }
#pragma unroll
        for (int r = 0; r < 4; r++) {
            int j = j0 + r;
            int k   = (j >= HW) + (j >= 2 * HW);
            int pix = j - k * HW;
            bool pos = (bn[r] + bn[r] >= bu[r]);   // max_iou >= 0.5
            bool neg = (bn[r] < 0.3f * bu[r]);     // max_iou <  0.3
            unsigned key = 0u;
            if (neg) key = mapf(objbase[(size_t)k * 8 * HW + pix]);
            s_key[j] = key;
            s_mf[j]  = (unsigned short)(at_[r] | (pos ? 0x100 : 0) | (neg ? 0x200 : 0));
        }
    }

    // ---- windowed per-box best anchor (one wave per box) -------------------
    for (int t = wid; t < T; t += 16) {
        float4 g = s_box[t];
        float  ab = s_ab[t];
        int px0 = max(0, (int)floorf(g.x / stf) - 2);
        int px1 = min(W - 1, (int)floorf(g.z / stf) + 2);
        int py0 = max(0, (int)floorf(g.y / stf) - 2);
        int py1 = min(W - 1, (int)floorf(g.w / stf) + 2);
        int rowlen = (px1 - px0 + 1) * 3;
        float bi = -1.f, bu2 = 1.f;
        int ba = 0;
        for (int py = py0; py <= py1; py++) {
            float cy = ((float)py + 0.5f) * stf;
            for (int cc = lane; cc < rowlen; cc += 64) {
                int ix = (cc * 21846) >> 16;   // /3
                int k  = cc - 3 * ix;
                int px = px0 + ix;
                float w  = (2.0f + 0.5f * (float)k) * stf;
                float cx = ((float)px + 0.5f) * stf;
                float lx = fmaxf(cx - 0.5f * w, g.x), ly = fmaxf(cy - 0.5f * w, g.y);
                float rx = fminf(cx + 0.5f * w, g.z), ry = fminf(cy + 0.5f * w, g.w);
                float ww = fmaxf(rx - lx, 0.f), hh = fmaxf(ry - ly, 0.f);
                float inter = ww * hh;
                float u = ((w * w + ab) - inter) + 1e-9f;
                if (inter * bu2 > bi * u) {
                    bi = inter; bu2 = u; ba = (py * W + px) * 3 + k;
                }
            }
        }
        for (int off = 32; off; off >>= 1) {
            float oi = __shfl_down(bi, off, 64);
            float ou = __shfl_down(bu2, off, 64);
            int   oa = __shfl_down(ba, off, 64);
            float l = oi * bu2, r = bi * ou;
            if (l > r || (l == r && oa < ba)) { bi = oi; bu2 = ou; ba = oa; }
        }
        if (lane == 0) {
            int pix = (ba * 21846) >> 16;   // /3
            int k = ba - 3 * pix;
            s_besta[t] = k * HW + pix;      // flattened j
        }
    }
    __syncthreads();   // match writes + s_besta complete

    // ---- forced-positive overrides (last t wins; distinct anchors) ---------
    if (tid < T) {
        int j20 = s_besta[tid];
        bool winner = true;
        for (int t2 = tid + 1; t2 < T; t2++) if (s_besta[t2] == j20) winner = false;
        if (winner) {
            s_mf[j20]  = (unsigned short)(tid | 0x100);
            s_key[j20] = 0u;
        }
    }
    __syncthreads();

    // ---- np/nn counted post-override ---------------------------------------
    unsigned npnn = 0;
    for (int j = tid; j < A; j += 1024) {
        unsigned m = s_mf[j];
        npnn += ((m >> 8) & 1u) + (((m >> 9) & 1u) << 16);
    }
    for (int off = 32; off; off >>= 1) npnn += (unsigned)__shfl_down((int)npnn, off, 64);
    if (lane == 0) atomicAdd(&s_npnn, npnn);
    __syncthreads();
    unsigned np = s_npnn & 0xFFFFu, nn = s_npnn >> 16;
    unsigned need = min(3u * np, nn);

    // ---- exact k-th largest neg key: 4x8-bit radix, wave-quad hists --------
    unsigned kth = 0xFFFFFFFFu;
    if (need > 0) {
        unsigned prefix = 0, remaining = need;
        for (int p = 0; p < 4; p++) {
            const int sh_ = 24 - 8 * p;
            (&whist[0][0])[tid] = 0u;   // 1024 threads zero 1024 bins
            __syncthreads();
            for (int j = tid; j < A; j += 1024) {
                unsigned k = s_key[j];
                bool ok = (p == 0) || ((k >> (sh_ + 8)) == prefix);
                if (ok) atomicAdd(&whist[wid >> 2][(k >> sh_) & 255u], 1u);
            }
            __syncthreads();
            if (tid < 256) {
                whist[0][tid] = whist[0][tid] + whist[1][tid]
                              + whist[2][tid] + whist[3][tid];
            }
            __syncthreads();
            if (wid == 0) {
                int b0 = lane * 4;
                unsigned csum = whist[0][b0] + whist[0][b0 + 1]
                              + whist[0][b0 + 2] + whist[0][b0 + 3];
                unsigned Tv = csum;
                for (int off = 1; off < 64; off <<= 1) {
                    unsigned o = __shfl_down(Tv, off, 64);
                    if (lane + off < 64) Tv += o;
                }
                // Tv = suffix sum over bins >= b0 (non-increasing in lane)
                unsigned long long ball = __ballot(Tv >= remaining);
                int L = 63 - __clzll(ball);
                if (lane == L) {
                    unsigned sv = Tv - csum;   // count strictly above chunk
                    int bb = b0 + 3;
                    while (true) { sv += whist[0][bb]; if (sv >= remaining) break; bb--; }
                    s_bc[0] = (unsigned)bb;
                    s_bc[1] = sv - whist[0][bb];  // strictly above bin bb
                }
            }
            __syncthreads();
            remaining -= s_bc[1];
            prefix = (prefix << 8) | s_bc[0];
            __syncthreads();
        }
        kth = prefix;
    }

    // ---- losses ------------------------------------------------------------
    float obj_s = 0.f, cls_s = 0.f, loc_s = 0.f;
    unsigned cgt = 0;
    for (int j = tid; j < A; j += 1024) {
        unsigned mfv = s_mf[j];
        if (mfv & 0x100u) {
            int k   = (j >= HW) + (j >= 2 * HW);
            int pix = j - k * HW;
            const float* bp = pred + (size_t)(b * 24 + k * 8) * HW + pix;
            float x = bp[(size_t)4 * HW];
            obj_s += bce_pos(x);
            int t = mfv & 0xFFu;
            float4 g = s_box[t];
            int tgt = s_lab[t] - 1;
            float c0 = bp[(size_t)5 * HW], c1 = bp[(size_t)6 * HW], c2 = bp[(size_t)7 * HW];
            float mm  = fmaxf(c0, fmaxf(c1, c2));
            float lse = logf(expf(c0 - mm) + expf(c1 - mm) + expf(c2 - mm));
            float ct = (tgt == 0) ? c0 : (tgt == 1) ? c1 : c2;
            cls_s += (mm + lse) - ct;
            int qq = pix >> sh;
            int py = (qq * 9363) >> 16;
            int px = pix - py * W;
            float w  = (2.0f + 0.5f * (float)k) * stf;
            float cx = ((float)px + 0.5f) * stf;
            float cy = ((float)py + 0.5f) * stf;
            float gcx = (g.x + g.z) * 0.5f, gcy = (g.y + g.w) * 0.5f;
            float gw = g.z - g.x, gh = g.w - g.y;
            float t0 = (gcx - cx) / w, t1 = (gcy - cy) / w;
            float t2 = logf(gw / w),   t3 = logf(gh / w);
            float d0 = bp[0], d1 = bp[(size_t)HW], d2 = bp[(size_t)2 * HW], d3 = bp[(size_t)3 * HW];
            float dd;
            dd = fabsf(d0 - t0); loc_s += (dd < 1.f) ? 0.5f * dd * dd : dd - 0.5f;
            dd = fabsf(d1 - t1); loc_s += (dd < 1.f) ? 0.5f * dd * dd : dd - 0.5f;
            dd = fabsf(d2 - t2); loc_s += (dd < 1.f) ? 0.5f * dd * dd : dd - 0.5f;
            dd = fabsf(d3 - t3); loc_s += (dd < 1.f) ? 0.5f * dd * dd : dd - 0.5f;
        } else {
            unsigned key = s_key[j];
            if (key > kth) { obj_s += bce_neg(unmapf(key)); cgt++; }
        }
    }
    for (int off = 32; off; off >>= 1) {
        obj_s += __shfl_down(obj_s, off, 64);
        cls_s += __shfl_down(cls_s, off, 64);
        loc_s += __shfl_down(loc_s, off, 64);
        cgt   += (unsigned)__shfl_down((int)cgt, off, 64);
    }
    if (lane == 0) {
        s_redf[wid * 4 + 0] = obj_s;
        s_redf[wid * 4 + 1] = cls_s;
        s_redf[wid * 4 + 2] = loc_s;
        s_redf[wid * 4 + 3] = __uint_as_float(cgt);
    }
    __syncthreads();
    if (tid == 0) {
        float ob = 0.f, cl = 0.f, lc = 0.f;
        unsigned cg = 0;
        for (int w2 = 0; w2 < 16; w2++) {
            ob += s_redf[w2 * 4 + 0];
            cl += s_redf[w2 * 4 + 1];
            lc += s_redf[w2 * 4 + 2];
            cg += __float_as_uint(s_redf[w2 * 4 + 3]);
        }
        if (need > 0) ob += (float)(need - cg) * bce_neg(unmapf(kth));
        wsf[LOSS_OFF + bid * 3 + 0] = ob / (float)max(np + need, 1u);
        wsf[LOSS_OFF + bid * 3 + 1] = cl / (float)max(np, 1u);
        wsf[LOSS_OFF + bid * 3 + 2] = lc / (float)max(4u * np, 1u);
    }
}

__global__ void finalize_kernel(const float* __restrict__ wsf,
                                float* __restrict__ out) {
    const int t = threadIdx.x, lane = t & 63, wid = t >> 6;
    __shared__ float red[12];
    float v0 = 0.f, v1 = 0.f, v2 = 0.f;
    if (t < 192) {
        v0 = wsf[LOSS_OFF + 3 * t];
        v1 = wsf[LOSS_OFF + 3 * t + 1];
        v2 = wsf[LOSS_OFF + 3 * t + 2];
    }
    for (int off = 32; off; off >>= 1) {
        v0 += __shfl_down(v0, off, 64);
        v1 += __shfl_down(v1, off, 64);
        v2 += __shfl_down(v2, off, 64);
    }
    if (lane == 0) { red[wid * 3] = v0; red[wid * 3 + 1] = v1; red[wid * 3 + 2] = v2; }
    __syncthreads();
    if (t == 0) {
        float obj = 0.f, cls = 0.f, loc = 0.f;
        for (int w2 = 0; w2 < 4; w2++) {
            obj += red[w2 * 3]; cls += red[w2 * 3 + 1]; loc += red[w2 * 3 + 2];
        }
        obj /= 64.f; cls /= 64.f; loc /= 64.f;
        out[0] = obj; out[1] = cls; out[2] = loc;
        out[3] = obj + cls + 2.f * loc;
    }
}

extern "C" void kernel_launch(void* const* d_in, const int* in_sizes, int n_in,
                              void* d_out, int out_size, void* d_ws, size_t ws_size,
                              hipStream_t stream) {
    const float* pred1   = (const float*)d_in[0];
    const float* pred2   = (const float*)d_in[1];
    const float* pred3   = (const float*)d_in[2];
    const float* tboxes  = (const float*)d_in[6];
    const int*   tlabels = (const int*)d_in[7];
    float* wsf = (float*)d_ws;
    float* out = (float*)d_out;

    fused_kernel<<<64 * 3, 1024, 0, stream>>>(
        pred1, pred2, pred3, tboxes, tlabels, wsf);
    finalize_kernel<<<1, 256, 0, stream>>>(wsf, out);
}

// Round 8
// 115.773 us; speedup vs baseline: 1.1673x; 1.0094x over previous
//
#include <hip/hip_runtime.h>
#include <math.h>

#define T 20
#define MAXA 9408
#define LOSS_OFF 16          // float index into ws: 192*3 loss triples

static __device__ __forceinline__ unsigned mapf(float x) {
    unsigned u = __float_as_uint(x);
    return (u & 0x80000000u) ? ~u : (u | 0x80000000u);
}
static __device__ __forceinline__ float unmapf(unsigned m) {
    return __uint_as_float((m & 0x80000000u) ? (m ^ 0x80000000u) : ~m);
}
static __device__ __forceinline__ float bce_pos(float x) {
    return fmaxf(x, 0.f) - x + log1pf(expf(-fabsf(x)));
}
static __device__ __forceinline__ float bce_neg(float x) {
    return fmaxf(x, 0.f) + log1pf(expf(-fabsf(x)));
}

// flag encoding (u8): bits 0-4 = matched_t, 0x20 = pos, 0x40 = neg

// ---------------------------------------------------------------------------
// Fused per-(b,s) kernel, 192 blocks x 1024. All per-anchor state in LDS.
// Obj prefetch at group top; np/nn fused into match + analytic override
// adjust; 3-pass radix select (11/11/10 bits) on a single 2048-bin histogram.
// ---------------------------------------------------------------------------
__global__ __launch_bounds__(1024, 1) void fused_kernel(
    const float* __restrict__ pred1, const float* __restrict__ pred2,
    const float* __restrict__ pred3, const float* __restrict__ tboxes,
    const int* __restrict__ tlabels, float* __restrict__ wsf)
{
#pragma clang fp contract(off)
    const int bid = blockIdx.x;
    const int b = bid / 3, s = bid - 3 * b;
    const float* __restrict__ pred = (s == 0) ? pred1 : (s == 1) ? pred2 : pred3;
    const int W = 56 >> s, HW = W * W, A = 3 * HW;
    const float stf = (float)(8 << s);
    const int sh = 3 - s;

    __shared__ unsigned      s_key[MAXA];   // 37632 B
    __shared__ unsigned char s_mf[MAXA];    //  9408 B
    __shared__ unsigned      hist[2048];    //  8192 B
    __shared__ float4   s_box[T];
    __shared__ float    s_ab[T];
    __shared__ int      s_lab[T];
    __shared__ int      s_besta[T];
    __shared__ unsigned s_npnn, s_adj;
    __shared__ unsigned s_bc[2];
    __shared__ float    s_redf[16 * 4];

    const int tid = threadIdx.x, lane = tid & 63, wid = tid >> 6;

    if (tid < T) {
        float4 g = ((const float4*)tboxes)[b * T + tid];
        s_box[tid] = g;
        s_ab[tid]  = (g.z - g.x) * (g.w - g.y);
        s_lab[tid] = tlabels[b * T + tid];
    }
    if (tid == 0) { s_npnn = 0u; s_adj = 0u; }
    __syncthreads();

    const float* objbase = pred + (size_t)(b * 24 + 4) * HW;

    // ---- P1 match: groups of 4 contiguous anchors (HW%4==0 -> same k slab);
    //      obj prefetch issued first, hidden behind the 20-box loop ----------
    unsigned npnn = 0;
    for (int j0 = 4 * tid; j0 < A; j0 += 4096) {
        int k    = (j0 >= HW) + (j0 >= 2 * HW);
        int pix0 = j0 - k * HW;
        const float* op = objbase + (size_t)k * 8 * HW + pix0;
        float xo0 = op[0], xo1 = op[1], xo2 = op[2], xo3 = op[3];

        float ax[4], ay[4], az[4], aw[4], ar[4], bn[4], bu[4];
        int at_[4];
        float xlo = 1e30f, xhi = -1e30f, ylo = 1e30f, yhi = -1e30f;
#pragma unroll
        for (int r = 0; r < 4; r++) {
            int pix = pix0 + r;
            int qq  = pix >> sh;
            int py  = (qq * 9363) >> 16;      // exact /7 for qq<=448
            int px  = pix - py * W;
            float w  = (2.0f + 0.5f * (float)k) * stf;   // exact f32
            float cx = ((float)px + 0.5f) * stf;
            float cy = ((float)py + 0.5f) * stf;
            ax[r] = cx - 0.5f * w; ay[r] = cy - 0.5f * w;
            az[r] = cx + 0.5f * w; aw[r] = cy + 0.5f * w;
            ar[r] = w * w;
            bn[r] = 0.f; bu[r] = 1.f; at_[r] = 0;   // iou==0 -> argmax t=0
            xlo = fminf(xlo, ax[r]); xhi = fmaxf(xhi, az[r]);
            ylo = fminf(ylo, ay[r]); yhi = fmaxf(yhi, aw[r]);
        }
        for (int t = 0; t < T; t++) {
            float4 g = s_box[t];
            // disjoint from the 4-anchor band => IoU exactly 0 => skip
            if (g.x < xhi && g.z > xlo && g.y < yhi && g.w > ylo) {
                float ab = s_ab[t];
#pragma unroll
                for (int r = 0; r < 4; r++) {
                    float lx = fmaxf(ax[r], g.x), ly = fmaxf(ay[r], g.y);
                    float rx = fminf(az[r], g.z), ry = fminf(aw[r], g.w);
                    float ww = fmaxf(rx - lx, 0.f), hh = fmaxf(ry - ly, 0.f);
                    float inter = ww * hh;
                    float u = ((ar[r] + ab) - inter) + 1e-9f;
                    if (inter * bu[r] > bn[r] * u) {
                        bn[r] = inter; bu[r] = u; at_[r] = t;
                    }
                }
            }
        }
        float xo[4] = {xo0, xo1, xo2, xo3};
#pragma unroll
        for (int r = 0; r < 4; r++) {
            int j = j0 + r;
            bool pos = (bn[r] + bn[r] >= bu[r]);   // max_iou >= 0.5
            bool neg = (bn[r] < 0.3f * bu[r]);     // max_iou <  0.3
            s_key[j] = neg ? mapf(xo[r]) : 0u;
            s_mf[j]  = (unsigned char)(at_[r] | (pos ? 0x20 : 0) | (neg ? 0x40 : 0));
            npnn += (pos ? 1u : 0u) + (neg ? 0x10000u : 0u);
        }
    }
    for (int off = 32; off; off >>= 1) npnn += (unsigned)__shfl_down((int)npnn, off, 64);
    if (lane == 0) atomicAdd(&s_npnn, npnn);

    // ---- P2 windowed per-box best anchor (one wave per box) ----------------
    for (int t = wid; t < T; t += 16) {
        float4 g = s_box[t];
        float  ab = s_ab[t];
        int px0 = max(0, (int)floorf(g.x / stf) - 2);
        int px1 = min(W - 1, (int)floorf(g.z / stf) + 2);
        int py0 = max(0, (int)floorf(g.y / stf) - 2);
        int py1 = min(W - 1, (int)floorf(g.w / stf) + 2);
        int rowlen = (px1 - px0 + 1) * 3;
        float bi = -1.f, bu2 = 1.f;
        int ba = 0;
        for (int py = py0; py <= py1; py++) {
            float cy = ((float)py + 0.5f) * stf;
            for (int cc = lane; cc < rowlen; cc += 64) {
                int ix = (cc * 21846) >> 16;   // /3
                int k  = cc - 3 * ix;
                int px = px0 + ix;
                float w  = (2.0f + 0.5f * (float)k) * stf;
                float cx = ((float)px + 0.5f) * stf;
                float lx = fmaxf(cx - 0.5f * w, g.x), ly = fmaxf(cy - 0.5f * w, g.y);
                float rx = fminf(cx + 0.5f * w, g.z), ry = fminf(cy + 0.5f * w, g.w);
                float ww = fmaxf(rx - lx, 0.f), hh = fmaxf(ry - ly, 0.f);
                float inter = ww * hh;
                float u = ((w * w + ab) - inter) + 1e-9f;
                if (inter * bu2 > bi * u) {
                    bi = inter; bu2 = u; ba = (py * W + px) * 3 + k;
                }
            }
        }
        for (int off = 32; off; off >>= 1) {
            float oi = __shfl_down(bi, off, 64);
            float ou = __shfl_down(bu2, off, 64);
            int   oa = __shfl_down(ba, off, 64);
            float l = oi * bu2, r = bi * ou;
            if (l > r || (l == r && oa < ba)) { bi = oi; bu2 = ou; ba = oa; }
        }
        if (lane == 0) {
            int pix = (ba * 21846) >> 16;   // /3
            int k = ba - 3 * pix;
            s_besta[t] = k * HW + pix;      // flattened j
        }
    }
    __syncthreads();   // P1 writes + s_besta complete

    // ---- P3: override count-adjust (first occurrence) + zero hist ----------
    int  j20 = 0; bool winner = false;
    if (tid < T) {
        int a = s_besta[tid];
        j20 = a;
        winner = true; bool first = true;
        for (int t2 = tid + 1; t2 < T; t2++) if (s_besta[t2] == a) winner = false;
        for (int t2 = 0; t2 < tid; t2++)     if (s_besta[t2] == a) first  = false;
        if (first) {
            unsigned old = s_mf[a];
            unsigned d = ((old & 0x20u) ? 0u : 1u) +
                         ((old & 0x40u) ? 0xFFFF0000u : 0u);  // nn -= 1
            atomicAdd(&s_adj, d);
        }
    }
    hist[tid] = 0u; hist[tid + 1024] = 0u;
    __syncthreads();

    // ---- P4: apply overrides (last t wins; winners hit distinct anchors) ---
    if (tid < T && winner) {
        s_mf[j20]  = (unsigned char)(tid | 0x20);
        s_key[j20] = 0u;
    }
    __syncthreads();

    unsigned packed = s_npnn + s_adj;
    unsigned np = packed & 0xFFFFu, nn = packed >> 16;
    unsigned need = min(3u * np, nn);

    // ---- P5: exact k-th largest neg key, 3-pass radix (11/11/10 bits) ------
    unsigned kth = 0xFFFFFFFFu;
    if (need > 0) {
        unsigned prefix = 0, remaining = need;
        const int shifts[3] = {21, 10, 0};
        const int nbits[3]  = {11, 11, 10};
        for (int p = 0; p < 3; p++) {
            const int NB = 1 << nbits[p];
            const int sh_ = shifts[p];
            for (int j = tid; j < A; j += 1024) {
                unsigned k = s_key[j];
                bool ok = (p == 0) || ((k >> (sh_ + nbits[p])) == prefix);
                if (ok) atomicAdd(&hist[(k >> sh_) & (NB - 1)], 1u);
            }
            __syncthreads();
            if (wid == 0) {
                const int C = NB >> 6;
                int b0 = lane * C;
                unsigned csum = 0;
                for (int i = 0; i < C; i++) csum += hist[b0 + i];
                unsigned Tv = csum;
                for (int off = 1; off < 64; off <<= 1) {
                    unsigned o = __shfl_down(Tv, off, 64);
                    if (lane + off < 64) Tv += o;
                }
                // Tv = suffix sum over bins >= b0 (non-increasing in lane)
                unsigned long long ball = __ballot(Tv >= remaining);
                int L = 63 - __clzll(ball);
                if (lane == L) {
                    unsigned sv = Tv - csum;   // count strictly above chunk
                    int bb = b0 + C - 1;
                    while (true) { sv += hist[bb]; if (sv >= remaining) break; bb--; }
                    s_bc[0] = (unsigned)bb;
                    s_bc[1] = sv - hist[bb];   // strictly above bin bb
                }
            }
            __syncthreads();
            remaining -= s_bc[1];
            prefix = (prefix << nbits[p]) | s_bc[0];
            if (p < 2) { hist[tid] = 0u; hist[tid + 1024] = 0u; }
            __syncthreads();
        }
        kth = prefix;
    }

    // ---- P6: losses --------------------------------------------------------
    float obj_s = 0.f, cls_s = 0.f, loc_s = 0.f;
    unsigned cgt = 0;
    for (int j = tid; j < A; j += 1024) {
        unsigned mfv = s_mf[j];
        if (mfv & 0x20u) {
            int k   = (j >= HW) + (j >= 2 * HW);
            int pix = j - k * HW;
            const float* bp = pred + (size_t)(b * 24 + k * 8) * HW + pix;
            float x = bp[(size_t)4 * HW];
            obj_s += bce_pos(x);
            int t = mfv & 0x1Fu;
            float4 g = s_box[t];
            int tgt = s_lab[t] - 1;
            float c0 = bp[(size_t)5 * HW], c1 = bp[(size_t)6 * HW], c2 = bp[(size_t)7 * HW];
            float mm  = fmaxf(c0, fmaxf(c1, c2));
            float lse = logf(expf(c0 - mm) + expf(c1 - mm) + expf(c2 - mm));
            float ct = (tgt == 0) ? c0 : (tgt == 1) ? c1 : c2;
            cls_s += (mm + lse) - ct;
            int qq = pix >> sh;
            int py = (qq * 9363) >> 16;
            int px = pix - py * W;
            float w  = (2.0f + 0.5f * (float)k) * stf;
            float cx = ((float)px + 0.5f) * stf;
            float cy = ((float)py + 0.5f) * stf;
            float gcx = (g.x + g.z) * 0.5f, gcy = (g.y + g.w) * 0.5f;
            float gw = g.z - g.x, gh = g.w - g.y;
            float t0 = (gcx - cx) / w, t1 = (gcy - cy) / w;
            float t2 = logf(gw / w),   t3 = logf(gh / w);
            float d0 = bp[0], d1 = bp[(size_t)HW], d2 = bp[(size_t)2 * HW], d3 = bp[(size_t)3 * HW];
            float dd;
            dd = fabsf(d0 - t0); loc_s += (dd < 1.f) ? 0.5f * dd * dd : dd - 0.5f;
            dd = fabsf(d1 - t1); loc_s += (dd < 1.f) ? 0.5f * dd * dd : dd - 0.5f;
            dd = fabsf(d2 - t2); loc_s += (dd < 1.f) ? 0.5f * dd * dd : dd - 0.5f;
            dd = fabsf(d3 - t3); loc_s += (dd < 1.f) ? 0.5f * dd * dd : dd - 0.5f;
        } else {
            unsigned key = s_key[j];
            if (key > kth) { obj_s += bce_neg(unmapf(key)); cgt++; }
        }
    }
    for (int off = 32; off; off >>= 1) {
        obj_s += __shfl_down(obj_s, off, 64);
        cls_s += __shfl_down(cls_s, off, 64);
        loc_s += __shfl_down(loc_s, off, 64);
        cgt   += (unsigned)__shfl_down((int)cgt, off, 64);
    }
    if (lane == 0) {
        s_redf[wid * 4 + 0] = obj_s;
        s_redf[wid * 4 + 1] = cls_s;
        s_redf[wid * 4 + 2] = loc_s;
        s_redf[wid * 4 + 3] = __uint_as_float(cgt);
    }
    __syncthreads();
    if (tid == 0) {
        float ob = 0.f, cl = 0.f, lc = 0.f;
        unsigned cg = 0;
        for (int w2 = 0; w2 < 16; w2++) {
            ob += s_redf[w2 * 4 + 0];
            cl += s_redf[w2 * 4 + 1];
            lc += s_redf[w2 * 4 + 2];
            cg += __float_as_uint(s_redf[w2 * 4 + 3]);
        }
        if (need > 0) ob += (float)(need - cg) * bce_neg(unmapf(kth));
        wsf[LOSS_OFF + bid * 3 + 0] = ob / (float)max(np + need, 1u);
        wsf[LOSS_OFF + bid * 3 + 1] = cl / (float)max(np, 1u);
        wsf[LOSS_OFF + bid * 3 + 2] = lc / (float)max(4u * np, 1u);
    }
}

__global__ void finalize_kernel(const float* __restrict__ wsf,
                                float* __restrict__ out) {
    const int t = threadIdx.x, lane = t & 63, wid = t >> 6;
    __shared__ float red[12];
    float v0 = 0.f, v1 = 0.f, v2 = 0.f;
    if (t < 192) {
        v0 = wsf[LOSS_OFF + 3 * t];
        v1 = wsf[LOSS_OFF + 3 * t + 1];
        v2 = wsf[LOSS_OFF + 3 * t + 2];
    }
    for (int off = 32; off; off >>= 1) {
        v0 += __shfl_down(v0, off, 64);
        v1 += __shfl_down(v1, off, 64);
        v2 += __shfl_down(v2, off, 64);
    }
    if (lane == 0) { red[wid * 3] = v0; red[wid * 3 + 1] = v1; red[wid * 3 + 2] = v2; }
    __syncthreads();
    if (t == 0) {
        float obj = 0.f, cls = 0.f, loc = 0.f;
        for (int w2 = 0; w2 < 4; w2++) {
            obj += red[w2 * 3]; cls += red[w2 * 3 + 1]; loc += red[w2 * 3 + 2];
        }
        obj /= 64.f; cls /= 64.f; loc /= 64.f;
        out[0] = obj; out[1] = cls; out[2] = loc;
        out[3] = obj + cls + 2.f * loc;
    }
}

extern "C" void kernel_launch(void* const* d_in, const int* in_sizes, int n_in,
                              void* d_out, int out_size, void* d_ws, size_t ws_size,
                              hipStream_t stream) {
    const float* pred1   = (const float*)d_in[0];
    const float* pred2   = (const float*)d_in[1];
    const float* pred3   = (const float*)d_in[2];
    const float* tboxes  = (const float*)d_in[6];
    const int*   tlabels = (const int*)d_in[7];
    float* wsf = (float*)d_ws;
    float* out = (float*)d_out;

    fused_kernel<<<64 * 3, 1024, 0, stream>>>(
        pred1, pred2, pred3, tboxes, tlabels, wsf);
    finalize_kernel<<<1, 256, 0, stream>>>(wsf, out);
}